// Round 10
// baseline (261.940 us; speedup 1.0000x reference)
//
#include <hip/hip_runtime.h>
#include <hip/hip_bf16.h>
#include <math.h>
#include <stdint.h>
#include <string.h>

#define BB 8
#define SS 96
#define DD 768
#define RR 24
#define RSEQ 8
#define TAG 3
#define D3 2304   // 3*D
#define NC 72     // R*TAG

typedef __attribute__((ext_vector_type(8))) short bf16x8;
typedef __attribute__((ext_vector_type(4))) float f32x4;

// async global->LDS, 16 B/lane; LDS dest = wave-uniform base + lane*16.
typedef __attribute__((address_space(3))) uint8_t lds_u8;
typedef const __attribute__((address_space(1))) uint8_t glb_u8;
static __device__ __forceinline__ void glld16(const void* g, void* l) {
  __builtin_amdgcn_global_load_lds((glb_u8*)g, (lds_u8*)l, 16, 0, 0);
}

// round-half-up f32 pair -> packed bf16x2: add,add,v_perm = 3 VALU.
static __device__ inline uint32_t pkrhu(float lo, float hi) {
  uint32_t a, b;
  memcpy(&a, &lo, 4);
  memcpy(&b, &hi, 4);
  return __builtin_amdgcn_perm(b + 0x8000u, a + 0x8000u, 0x07060302u);
}
static __device__ inline uint16_t bf16c(float v) {
  uint32_t u;
  memcpy(&u, &v, 4);
  u += 0x7FFFu + ((u >> 16) & 1u);
  return (uint16_t)(u >> 16);
}
static __device__ inline uint32_t pkrne(float lo, float hi) {
  uint32_t a, b;
  memcpy(&a, &lo, 4);
  memcpy(&b, &hi, 4);
  a += 0x7FFFu + ((a >> 16) & 1u);
  b += 0x7FFFu + ((b >> 16) & 1u);
  return (a >> 16) | (b & 0xFFFF0000u);
}
static __device__ inline float lo16f(uint32_t u) {
  const uint32_t v = u << 16;
  float f;
  memcpy(&f, &v, 4);
  return f;
}
static __device__ inline float hi16f(uint32_t u) {
  const uint32_t v = u & 0xFFFF0000u;
  float f;
  memcpy(&f, &v, 4);
  return f;
}

// ---------------------------------------------------------------------------
// Kernel 0 (fused prep): blocks 0..35 = prepW, 36..899 = proj_W transpose,
// 900..907 = S0/G (the parallel part of refine). One launch, independent work.
// ---------------------------------------------------------------------------
__global__ __launch_bounds__(256) void k_prep0(const float* __restrict__ relW,
                                               uint16_t* __restrict__ Wb,
                                               const float* __restrict__ projW,
                                               uint16_t* __restrict__ Tp,
                                               const float* __restrict__ enc,
                                               const float* __restrict__ rel,
                                               float* __restrict__ SG) {
  __shared__ __align__(16) char smem[24704];
  const int blk = blockIdx.x;
  const int t = threadIdx.x;

  if (blk < 36) {
    // ---- Wb[96][2304] bf16 = rel_W^T (rows 72..79 zero; 80..95 untouched) ----
    float* tile = (float*)smem;  // 64*72 f32
    const int k0 = blk * 64;
    const float* src = relW + (size_t)k0 * NC;
    for (int e = t; e < 64 * NC / 4; e += 256) ((float4*)tile)[e] = ((const float4*)src)[e];
    __syncthreads();
    for (int u = t; u < 80 * 16; u += 256) {
      const int n = u >> 4, kq = (u & 15) * 4;
      uint2 w = {0u, 0u};
      if (n < NC) {
        w.x = pkrne(tile[(kq + 0) * NC + n], tile[(kq + 1) * NC + n]);
        w.y = pkrne(tile[(kq + 2) * NC + n], tile[(kq + 3) * NC + n]);
      }
      *(uint2*)&Wb[(size_t)n * D3 + k0 + kq] = w;
    }
  } else if (blk < 900) {
    // ---- Tp[2304][1536] bf16 = proj_W^T, 64x64 tile ----
    const int bx = blk - 36;
    float (*tile)[65] = (float(*)[65])smem;
    const int c0 = (bx % 36) * 64;
    const int r0 = (bx / 36) * 64;
    {
      const int tr = t >> 4;
      const int tc4 = (t & 15) * 4;
#pragma unroll
      for (int p = 0; p < 4; ++p) {
        const int r = tr + p * 16;
        const float4 v = *(const float4*)&projW[(size_t)(r0 + r) * D3 + c0 + tc4];
        tile[r][tc4 + 0] = v.x;
        tile[r][tc4 + 1] = v.y;
        tile[r][tc4 + 2] = v.z;
        tile[r][tc4 + 3] = v.w;
      }
    }
    __syncthreads();
    {
      const int cc = t >> 4;
      const int rr4 = (t & 15) * 4;
#pragma unroll
      for (int p = 0; p < 4; ++p) {
        const int c = cc + p * 16;
        uint2 w;
        w.x = pkrne(tile[rr4 + 0][c], tile[rr4 + 1][c]);
        w.y = pkrne(tile[rr4 + 2][c], tile[rr4 + 3][c]);
        *(uint2*)&Tp[(size_t)(c0 + c) * (2 * DD) + r0 + rr4] = w;
      }
    }
  } else {
    // ---- S0[8][96] and G[8][8] for sample b: one fused 8x104 product ----
    const int b = blk - 900;
    float (*As)[772] = (float(*)[772])smem;  // 8*772*4 = 24704 B
    const float* Ag = rel + (size_t)b * RSEQ * DD;
    for (int e = t; e < RSEQ * DD; e += 256) As[e / DD][e % DD] = Ag[e];
    __syncthreads();
    const float* Eb = enc + (size_t)b * SS * DD;
    for (int e = t; e < RSEQ * (SS + RSEQ); e += 256) {
      const int r = e & 7, s = e >> 3;
      const float* row = (s < SS) ? (Eb + (size_t)s * DD) : &As[s - SS][0];
      float a0 = 0.f, a1 = 0.f, a2 = 0.f, a3 = 0.f;
      for (int d = 0; d < DD; d += 4) {
        const float4 rv = *(const float4*)&row[d];
        a0 += As[r][d + 0] * rv.x;
        a1 += As[r][d + 1] * rv.y;
        a2 += As[r][d + 2] * rv.z;
        a3 += As[r][d + 3] * rv.w;
      }
      SG[((size_t)b * RSEQ + r) * 104 + s] = a0 + a1 + a2 + a3;
    }
  }
}

// ---------------------------------------------------------------------------
// Kernel 1a: refine serial core only — 24 collapsed attention steps on
// precomputed S0/G. Writes P[8][96]. grid 8.
// ---------------------------------------------------------------------------
__global__ __launch_bounds__(256) void k_refS(const float* __restrict__ SG,
                                              float* __restrict__ Pst) {
  const int b = blockIdx.x;
  const int t = threadIdx.x;
  __shared__ float S0[RSEQ][SS];
  __shared__ float G[RSEQ][RSEQ];
  __shared__ float P[RSEQ][SS];
  __shared__ float sc[RSEQ][SS];
  const float scale = 0.036084391824351613f;  // 1/sqrt(768)

  for (int e = t; e < RSEQ * 104; e += 256) {
    const int r = e / 104, c = e % 104;
    const float v = SG[(size_t)b * RSEQ * 104 + e];
    if (c < SS) S0[r][c] = v;
    else G[r][c - SS] = v;
  }
  for (int e = t; e < RSEQ * SS; e += 256) ((float*)P)[e] = 0.f;
  __syncthreads();

  const int wave = t >> 6, lane = t & 63;
  for (int step = 0; step < RR; ++step) {
    for (int e = t; e < RSEQ * SS; e += 256) {
      const int r = e / SS, s = e % SS;
      float acc = S0[r][s];
#pragma unroll
      for (int r2 = 0; r2 < RSEQ; ++r2) acc += G[r][r2] * P[r2][s];
      sc[r][s] = acc * scale;
    }
    __syncthreads();
#pragma unroll
    for (int rr = 0; rr < 2; ++rr) {
      const int r = wave * 2 + rr;
      const float m1 = sc[r][lane];
      const float m2 = (lane < 32) ? sc[r][lane + 64] : -1e30f;
      float mx = fmaxf(m1, m2);
#pragma unroll
      for (int o = 32; o > 0; o >>= 1) mx = fmaxf(mx, __shfl_xor(mx, o, 64));
      const float e1 = __expf(m1 - mx);
      const float e2 = (lane < 32) ? __expf(m2 - mx) : 0.f;
      float sm = e1 + e2;
#pragma unroll
      for (int o = 32; o > 0; o >>= 1) sm += __shfl_xor(sm, o, 64);
      const float inv = 1.f / sm;
      P[r][lane] += e1 * inv;
      if (lane < 32) P[r][lane + 64] += e2 * inv;
    }
    __syncthreads();
  }

  for (int e = t; e < RSEQ * SS; e += 256) Pst[(size_t)b * RSEQ * SS + e] = ((float*)P)[e];
}

// ---------------------------------------------------------------------------
// Kernel 1b: refine epilogue: enc' bf16 = enc + P^T @ A. grid 96 (8 rows/blk).
// ---------------------------------------------------------------------------
__global__ __launch_bounds__(256) void k_refB(const float* __restrict__ enc,
                                              const float* __restrict__ rel,
                                              const float* __restrict__ Pst,
                                              uint16_t* __restrict__ encRb) {
  const int blk = blockIdx.x;
  const int b = blk / 12;
  const int s0 = (blk % 12) * 8;
  const int t = threadIdx.x;
  __shared__ float As[RSEQ][DD + 4];
  __shared__ float Pl[RSEQ][8];

  const float* Ag = rel + (size_t)b * RSEQ * DD;
  for (int e = t; e < RSEQ * DD / 4; e += 256) {
    const int r = (e * 4) / DD, d = (e * 4) % DD;
    *(float4*)&As[r][d] = *(const float4*)&Ag[e * 4];
  }
  if (t < RSEQ * 8) {
    const int r = t >> 3, sl = t & 7;
    Pl[r][sl] = Pst[(size_t)b * RSEQ * SS + r * SS + s0 + sl];
  }
  __syncthreads();

  const float* Eb = enc + ((size_t)b * SS + s0) * DD;
  uint16_t* Ob = encRb + ((size_t)b * SS + s0) * DD;
  for (int e = t; e < 8 * DD / 4; e += 256) {
    const int sl = (e * 4) / DD, d = (e * 4) % DD;
    float4 v = ((const float4*)Eb)[e];
#pragma unroll
    for (int r = 0; r < RSEQ; ++r) {
      const float p = Pl[r][sl];
      v.x += p * As[r][d + 0];
      v.y += p * As[r][d + 1];
      v.z += p * As[r][d + 2];
      v.w += p * As[r][d + 3];
    }
    uint2 w;
    w.x = pkrhu(v.x, v.y);
    w.y = pkrhu(v.z, v.w);
    *(uint2*)&Ob[e * 4] = w;
  }
}

// ---------------------------------------------------------------------------
// Kernel 2: projection GEMM v2 — glld16-staged bf16 MFMA (no register
// round-trip for staging => compiler cannot serialize it). Tiles 64x64,
// BK=64, 4 waves 2x2 (wave 32x32). LDS rows stride 72 elems. grid (12,72).
// ---------------------------------------------------------------------------
__global__ __launch_bounds__(256, 4) void k_proj(const uint16_t* __restrict__ Ab,
                                                 const uint16_t* __restrict__ Bt,
                                                 const float* __restrict__ pb,
                                                 float* __restrict__ Hh,
                                                 uint16_t* __restrict__ Htb) {
  const int m0 = blockIdx.x * 64;
  const int gn0 = blockIdx.y * 64;
  const bool isH = gn0 < D3;               // uniform per block
  const int n0 = isH ? gn0 : gn0 - D3;
  const int halfk = isH ? 0 : DD;
  const int t = threadIdx.x, w = t >> 6, lane = t & 63;
  const int wm = w >> 1, wn = w & 1;
  const int lm = lane & 15, q = lane >> 4;

  __shared__ __align__(16) uint16_t As[64 * 72];  // 9216 B (rows: 64 data + 8 pad)
  __shared__ __align__(16) uint16_t Bs[64 * 72];  // 9216 B

  // staging pointers (k0-invariant): 18 issues of 1024 B (A:0..8, B:9..17)
  const char* rp[5];
  char* lp[5];
#pragma unroll
  for (int r = 0; r < 5; ++r) {
    const int idx = w + 4 * r;
    rp[r] = nullptr;
    lp[r] = nullptr;
    if (idx < 18) {
      const int ii = (idx < 9) ? idx : idx - 9;
      const int beta = ii * 1024 + lane * 16;
      const int elem = beta >> 1;
      const int row = elem / 72;
      int o = elem - row * 72;
      if (o >= 64) o = 0;  // pad lanes: safe addr, land in LDS row pad
      if (idx < 9) {
        rp[r] = (const char*)(Ab + (size_t)(m0 + row) * DD + o);
        lp[r] = (char*)As + ii * 1024;
      } else {
        rp[r] = (const char*)(Bt + (size_t)(n0 + row) * (2 * DD) + halfk + o);
        lp[r] = (char*)Bs + ii * 1024;
      }
    }
  }

  f32x4 acc[2][2];
#pragma unroll
  for (int a = 0; a < 2; ++a)
#pragma unroll
    for (int c = 0; c < 2; ++c) acc[a][c] = (f32x4){0.f, 0.f, 0.f, 0.f};

  for (int k0 = 0; k0 < DD; k0 += 64) {
    __syncthreads();
#pragma unroll
    for (int r = 0; r < 5; ++r)
      if (rp[r]) glld16(rp[r] + 2 * k0, lp[r]);
    __syncthreads();
#pragma unroll
    for (int kk = 0; kk < 2; ++kk) {
      const int ko = kk * 32 + q * 8;
      bf16x8 af[2], bf[2];
#pragma unroll
      for (int mt = 0; mt < 2; ++mt)
        af[mt] = *(const bf16x8*)&As[(wm * 32 + mt * 16 + lm) * 72 + ko];
#pragma unroll
      for (int nt = 0; nt < 2; ++nt)
        bf[nt] = *(const bf16x8*)&Bs[(wn * 32 + nt * 16 + lm) * 72 + ko];
#pragma unroll
      for (int nt = 0; nt < 2; ++nt)
#pragma unroll
        for (int mt = 0; mt < 2; ++mt)
          acc[mt][nt] = __builtin_amdgcn_mfma_f32_16x16x32_bf16(af[mt], bf[nt], acc[mt][nt], 0, 0, 0);
    }
  }

  // epilogue: C layout col=lm, row=q*4+r
#pragma unroll
  for (int nt = 0; nt < 2; ++nt) {
    const int ncol = n0 + wn * 32 + nt * 16 + lm;
    const int mrow = m0 + wm * 32 + q * 4;
    if (isH) {
      const float bias = pb[ncol];
#pragma unroll
      for (int mt = 0; mt < 2; ++mt)
#pragma unroll
        for (int r = 0; r < 4; ++r)
          Hh[(size_t)(mrow + mt * 16 + r) * D3 + ncol] = acc[mt][nt][r] + bias;
    } else {
#pragma unroll
      for (int mt = 0; mt < 2; ++mt)
#pragma unroll
        for (int r = 0; r < 4; ++r)
          Htb[(size_t)(mrow + mt * 16 + r) * D3 + ncol] = bf16c(acc[mt][nt][r]);
    }
  }
}

// ---------------------------------------------------------------------------
// Kernel 3: pairwise GEMM v7 — glld16 staging (v6 structure) with fatter
// wave tiles to cut LDS-read traffic (the measured bottleneck): 4 waves
// (256 thr) as 2x2, wave = 48j (3 mt) x {48,32}c ({3,2} nt). Reads per MFMA
// drop 0.9 -> 0.73 vs v6; A-build VALU total unchanged. grid 768 = (b,i).
// ---------------------------------------------------------------------------
#define HTS_B (96 * 144)                 // 13824 B staged Ht
#define STG_B (HTS_B + 80 * 144)         // 25344 B total
#define WOFF (HTS_B / 2)                 // 6912 elems

__global__ __launch_bounds__(256, 3) void k_pairs(const float* __restrict__ Hh,
                                                  const uint16_t* __restrict__ Htb,
                                                  const uint16_t* __restrict__ Wb,
                                                  const float* __restrict__ relb,
                                                  float* __restrict__ out) {
  const int bi = blockIdx.x;
  const int b = bi / SS, i = bi % SS;
  const int t = threadIdx.x;
  const int w = t >> 6, lane = t & 63;
  const int lm = lane & 15, q = lane >> 4;
  const int wm = w >> 1, wn = w & 1;
  const int ntn = wn ? 2 : 3;  // n-tiles this wave

  __shared__ __align__(16) float Hrow[D3];        // 9216 B (9 issues)
  __shared__ __align__(16) uint16_t Stg[12800];   // 25600 B (25 issues incl tail)

  // one-time: stage Hrow via async copy
  {
    const char* hh = (const char*)(Hh + (size_t)bi * D3);
#pragma unroll
    for (int r = 0; r < 3; ++r) {
      const int idx = w + 4 * r;
      if (idx < 9) glld16(hh + idx * 1024 + lane * 16, (char*)Hrow + idx * 1024);
    }
  }

  // per-lane k0-invariant source pointers for the 25 chunk-staging issues
  const char* rp[7];
#pragma unroll
  for (int r = 0; r < 7; ++r) {
    const int idx = w + 4 * r;
    rp[r] = nullptr;
    if (idx < 25) {
      const int beta = idx * 1024 + lane * 16;
      int elem, row, o;
      const char* base;
      if (beta < HTS_B) {
        elem = beta >> 1;
        row = elem / 72;
        o = elem - row * 72;
        base = (const char*)(Htb + ((size_t)b * SS + row) * D3);
      } else {
        elem = (beta - HTS_B) >> 1;
        row = elem / 72;
        o = elem - row * 72;
        base = (const char*)(Wb + (size_t)row * D3);  // rows up to 81 exist (96 alloc)
      }
      if (o >= 64) o = 0;  // pad lanes: valid addr, lands in unused LDS pad
      rp[r] = base + 2 * o;
    }
  }

  f32x4 acc[3][3];
#pragma unroll
  for (int mt = 0; mt < 3; ++mt)
#pragma unroll
    for (int nt = 0; nt < 3; ++nt) acc[mt][nt] = (f32x4){0.f, 0.f, 0.f, 0.f};

  for (int k0 = 0; k0 < D3; k0 += 64) {
    __syncthreads();  // prev chunk's Stg reads done (and orders Hrow on iter 0)
#pragma unroll
    for (int r = 0; r < 7; ++r) {
      const int idx = w + 4 * r;
      if (idx < 25) glld16(rp[r] + 2 * k0, (char*)Stg + idx * 1024);
    }
    __syncthreads();  // vmcnt drain: staged data visible

#pragma unroll
    for (int kk = 0; kk < 2; ++kk) {
      const int ko = kk * 32 + q * 8;
      const float4 h0 = *(const float4*)&Hrow[k0 + ko];      // broadcast
      const float4 h1 = *(const float4*)&Hrow[k0 + ko + 4];  // broadcast
      bf16x8 af[3];
#pragma unroll
      for (int mt = 0; mt < 3; ++mt) {
        const int j = wm * 48 + mt * 16 + lm;
        union { bf16x8 v; uint32_t u[4]; } hu, pk;
        hu.v = *(const bf16x8*)&Stg[j * 72 + ko];
        pk.u[0] = pkrhu(fmaxf(lo16f(hu.u[0]) + h0.x, 0.f), fmaxf(hi16f(hu.u[0]) + h0.y, 0.f));
        pk.u[1] = pkrhu(fmaxf(lo16f(hu.u[1]) + h0.z, 0.f), fmaxf(hi16f(hu.u[1]) + h0.w, 0.f));
        pk.u[2] = pkrhu(fmaxf(lo16f(hu.u[2]) + h1.x, 0.f), fmaxf(hi16f(hu.u[2]) + h1.y, 0.f));
        pk.u[3] = pkrhu(fmaxf(lo16f(hu.u[3]) + h1.z, 0.f), fmaxf(hi16f(hu.u[3]) + h1.w, 0.f));
        af[mt] = pk.v;
      }
#pragma unroll
      for (int nt = 0; nt < 3; ++nt) {
        if (nt < ntn) {
          const int n = (wn * 3 + nt) * 16 + lm;
          const bf16x8 bf = *(const bf16x8*)&Stg[WOFF + n * 72 + ko];
#pragma unroll
          for (int mt = 0; mt < 3; ++mt)
            acc[mt][nt] = __builtin_amdgcn_mfma_f32_16x16x32_bf16(af[mt], bf, acc[mt][nt], 0, 0, 0);
        }
      }
    }
  }

  // epilogue: C layout col=lm (c), row=q*4+r (j within 16-tile)
#pragma unroll
  for (int nt = 0; nt < 3; ++nt) {
    if (nt < ntn) {
      const int c = (wn * 3 + nt) * 16 + lm;
      if (c < NC) {
        const float rb = relb[c];
        const int rr = c / 3, tg = c % 3;
#pragma unroll
        for (int mt = 0; mt < 3; ++mt) {
          const int j0 = wm * 48 + mt * 16 + q * 4;
          float* base = out + ((((size_t)b * TAG + tg) * RR + rr) * SS + i) * SS + j0;
          float4 o;
          o.x = acc[mt][nt][0] + rb;
          o.y = acc[mt][nt][1] + rb;
          o.z = acc[mt][nt][2] + rb;
          o.w = acc[mt][nt][3] + rb;
          *(float4*)base = o;
        }
      }
    }
  }
}

// ---------------------------------------------------------------------------
extern "C" void kernel_launch(void* const* d_in, const int* in_sizes, int n_in,
                              void* d_out, int out_size, void* d_ws, size_t ws_size,
                              hipStream_t stream) {
  const float* enc   = (const float*)d_in[0];  // [8,96,768]
  const float* rel   = (const float*)d_in[1];  // [24,8,768]
  const float* projW = (const float*)d_in[2];  // [1536,2304]
  const float* projb = (const float*)d_in[3];  // [2304]
  const float* relW  = (const float*)d_in[4];  // [2304,72]
  const float* relb  = (const float*)d_in[5];  // [72]
  float* out = (float*)d_out;                  // [8,3,24,96,96]

  float* Hh = (float*)d_ws;                               // 768*2304 f32
  uint16_t* Htb = (uint16_t*)(Hh + (size_t)DD * D3);      // 768*2304 bf16
  uint16_t* Wb = Htb + (size_t)DD * D3;                   // 96*2304 bf16 (80 used)
  uint16_t* Tp = Wb + (size_t)96 * D3;                    // 2304*1536 bf16
  uint16_t* Ab = Tp + (size_t)D3 * 2 * DD;                // 768*768 bf16
  float* Pst = (float*)(Ab + (size_t)DD * DD);            // 8*8*96 f32
  float* SG = Pst + (size_t)BB * RSEQ * SS;               // 8*8*104 f32

  k_prep0<<<908, 256, 0, stream>>>(relW, Wb, projW, Tp, enc, rel, SG);
  k_refS<<<BB, 256, 0, stream>>>(SG, Pst);
  k_refB<<<96, 256, 0, stream>>>(enc, rel, Pst, Ab);
  k_proj<<<dim3(12, 72), 256, 0, stream>>>(Ab, Tp, projb, Hh, Htb);
  k_pairs<<<BB * SS, 256, 0, stream>>>(Hh, Htb, Wb, relb, out);
}

// Round 11
// 211.497 us; speedup vs baseline: 1.2385x; 1.2385x over previous
//
#include <hip/hip_runtime.h>
#include <hip/hip_bf16.h>
#include <math.h>
#include <stdint.h>
#include <string.h>

#define BB 8
#define SS 96
#define DD 768
#define RR 24
#define RSEQ 8
#define TAG 3
#define D3 2304   // 3*D
#define NC 72     // R*TAG

typedef __attribute__((ext_vector_type(8))) short bf16x8;
typedef __attribute__((ext_vector_type(4))) float f32x4;

// async global->LDS, 16 B/lane; LDS dest = wave-uniform base + lane*16.
typedef __attribute__((address_space(3))) uint8_t lds_u8;
typedef const __attribute__((address_space(1))) uint8_t glb_u8;
static __device__ __forceinline__ void glld16(const void* g, void* l) {
  __builtin_amdgcn_global_load_lds((glb_u8*)g, (lds_u8*)l, 16, 0, 0);
}

// round-half-up f32 pair -> packed bf16x2: add,add,v_perm = 3 VALU.
static __device__ inline uint32_t pkrhu(float lo, float hi) {
  uint32_t a, b;
  memcpy(&a, &lo, 4);
  memcpy(&b, &hi, 4);
  return __builtin_amdgcn_perm(b + 0x8000u, a + 0x8000u, 0x07060302u);
}
static __device__ inline uint16_t bf16c(float v) {
  uint32_t u;
  memcpy(&u, &v, 4);
  u += 0x7FFFu + ((u >> 16) & 1u);
  return (uint16_t)(u >> 16);
}
static __device__ inline uint32_t pkrne(float lo, float hi) {
  uint32_t a, b;
  memcpy(&a, &lo, 4);
  memcpy(&b, &hi, 4);
  a += 0x7FFFu + ((a >> 16) & 1u);
  b += 0x7FFFu + ((b >> 16) & 1u);
  return (a >> 16) | (b & 0xFFFF0000u);
}
static __device__ inline float lo16f(uint32_t u) {
  const uint32_t v = u << 16;
  float f;
  memcpy(&f, &v, 4);
  return f;
}
static __device__ inline float hi16f(uint32_t u) {
  const uint32_t v = u & 0xFFFF0000u;
  float f;
  memcpy(&f, &v, 4);
  return f;
}

// ---------------------------------------------------------------------------
// Kernel 0 (fused prep): blocks 0..35 = prepW, 36..899 = proj_W transpose,
// 900..1027 = S0/G k-split partial dots (8 samples x 16 chunks of 48 d's,
// atomicAdd into pre-zeroed SG). The old 8-block serial S0G was a ~75 µs
// latency tail (Occupancy 1.8%, VALUBusy 0.7% — R10 counters).
// ---------------------------------------------------------------------------
__global__ __launch_bounds__(256) void k_prep0(const float* __restrict__ relW,
                                               uint16_t* __restrict__ Wb,
                                               const float* __restrict__ projW,
                                               uint16_t* __restrict__ Tp,
                                               const float* __restrict__ enc,
                                               const float* __restrict__ rel,
                                               float* __restrict__ SG) {
  __shared__ __align__(16) char smem[24704];
  const int blk = blockIdx.x;
  const int t = threadIdx.x;

  if (blk < 36) {
    // ---- Wb[96][2304] bf16 = rel_W^T (rows 72..79 zero; 80..95 untouched) ----
    float* tile = (float*)smem;  // 64*72 f32
    const int k0 = blk * 64;
    const float* src = relW + (size_t)k0 * NC;
    for (int e = t; e < 64 * NC / 4; e += 256) ((float4*)tile)[e] = ((const float4*)src)[e];
    __syncthreads();
    for (int u = t; u < 80 * 16; u += 256) {
      const int n = u >> 4, kq = (u & 15) * 4;
      uint2 w = {0u, 0u};
      if (n < NC) {
        w.x = pkrne(tile[(kq + 0) * NC + n], tile[(kq + 1) * NC + n]);
        w.y = pkrne(tile[(kq + 2) * NC + n], tile[(kq + 3) * NC + n]);
      }
      *(uint2*)&Wb[(size_t)n * D3 + k0 + kq] = w;
    }
  } else if (blk < 900) {
    // ---- Tp[2304][1536] bf16 = proj_W^T, 64x64 tile ----
    const int bx = blk - 36;
    float (*tile)[65] = (float(*)[65])smem;
    const int c0 = (bx % 36) * 64;
    const int r0 = (bx / 36) * 64;
    {
      const int tr = t >> 4;
      const int tc4 = (t & 15) * 4;
#pragma unroll
      for (int p = 0; p < 4; ++p) {
        const int r = tr + p * 16;
        const float4 v = *(const float4*)&projW[(size_t)(r0 + r) * D3 + c0 + tc4];
        tile[r][tc4 + 0] = v.x;
        tile[r][tc4 + 1] = v.y;
        tile[r][tc4 + 2] = v.z;
        tile[r][tc4 + 3] = v.w;
      }
    }
    __syncthreads();
    {
      const int cc = t >> 4;
      const int rr4 = (t & 15) * 4;
#pragma unroll
      for (int p = 0; p < 4; ++p) {
        const int c = cc + p * 16;
        uint2 w;
        w.x = pkrne(tile[rr4 + 0][c], tile[rr4 + 1][c]);
        w.y = pkrne(tile[rr4 + 2][c], tile[rr4 + 3][c]);
        *(uint2*)&Tp[(size_t)(c0 + c) * (2 * DD) + r0 + rr4] = w;
      }
    }
  } else {
    // ---- S0/G partial: sample b, d-chunk [d0, d0+48). 832 (r,s) items,
    //      12 independent float4 loads each; atomicAdd into SG. ----
    const int idx = blk - 900;
    const int b = idx >> 4;
    const int d0 = (idx & 15) * 48;
    float (*AsF)[48] = (float(*)[48])smem;  // 8 x 48 f32 = 1.5 KB

    if (t < 96) {
      const int r = t / 12, q4 = (t % 12) * 4;
      *(float4*)&AsF[r][q4] = *(const float4*)&rel[((size_t)b * RSEQ + r) * DD + d0 + q4];
    }
    __syncthreads();

    for (int e = t; e < RSEQ * (SS + RSEQ); e += 256) {
      const int r = e & 7, s = e >> 3;
      const float* row = (s < SS) ? (enc + ((size_t)b * SS + s) * DD + d0) : &AsF[s - SS][0];
      float a0 = 0.f, a1 = 0.f, a2 = 0.f, a3 = 0.f;
#pragma unroll
      for (int d = 0; d < 48; d += 4) {
        const float4 rv = *(const float4*)&row[d];
        a0 += AsF[r][d + 0] * rv.x;
        a1 += AsF[r][d + 1] * rv.y;
        a2 += AsF[r][d + 2] * rv.z;
        a3 += AsF[r][d + 3] * rv.w;
      }
      atomicAdd(&SG[((size_t)b * RSEQ + r) * 104 + s], (a0 + a1) + (a2 + a3));
    }
  }
}

// ---------------------------------------------------------------------------
// Kernel 1a: refine serial core only — 24 collapsed attention steps on
// precomputed S0/G. Writes P[8][96]. grid 8.
// ---------------------------------------------------------------------------
__global__ __launch_bounds__(256) void k_refS(const float* __restrict__ SG,
                                              float* __restrict__ Pst) {
  const int b = blockIdx.x;
  const int t = threadIdx.x;
  __shared__ float S0[RSEQ][SS];
  __shared__ float G[RSEQ][RSEQ];
  __shared__ float P[RSEQ][SS];
  __shared__ float sc[RSEQ][SS];
  const float scale = 0.036084391824351613f;  // 1/sqrt(768)

  for (int e = t; e < RSEQ * 104; e += 256) {
    const int r = e / 104, c = e % 104;
    const float v = SG[(size_t)b * RSEQ * 104 + e];
    if (c < SS) S0[r][c] = v;
    else G[r][c - SS] = v;
  }
  for (int e = t; e < RSEQ * SS; e += 256) ((float*)P)[e] = 0.f;
  __syncthreads();

  const int wave = t >> 6, lane = t & 63;
  for (int step = 0; step < RR; ++step) {
    for (int e = t; e < RSEQ * SS; e += 256) {
      const int r = e / SS, s = e % SS;
      float acc = S0[r][s];
#pragma unroll
      for (int r2 = 0; r2 < RSEQ; ++r2) acc += G[r][r2] * P[r2][s];
      sc[r][s] = acc * scale;
    }
    __syncthreads();
#pragma unroll
    for (int rr = 0; rr < 2; ++rr) {
      const int r = wave * 2 + rr;
      const float m1 = sc[r][lane];
      const float m2 = (lane < 32) ? sc[r][lane + 64] : -1e30f;
      float mx = fmaxf(m1, m2);
#pragma unroll
      for (int o = 32; o > 0; o >>= 1) mx = fmaxf(mx, __shfl_xor(mx, o, 64));
      const float e1 = __expf(m1 - mx);
      const float e2 = (lane < 32) ? __expf(m2 - mx) : 0.f;
      float sm = e1 + e2;
#pragma unroll
      for (int o = 32; o > 0; o >>= 1) sm += __shfl_xor(sm, o, 64);
      const float inv = 1.f / sm;
      P[r][lane] += e1 * inv;
      if (lane < 32) P[r][lane + 64] += e2 * inv;
    }
    __syncthreads();
  }

  for (int e = t; e < RSEQ * SS; e += 256) Pst[(size_t)b * RSEQ * SS + e] = ((float*)P)[e];
}

// ---------------------------------------------------------------------------
// Kernel 1b: refine epilogue: enc' bf16 = enc + P^T @ A. grid 96 (8 rows/blk).
// ---------------------------------------------------------------------------
__global__ __launch_bounds__(256) void k_refB(const float* __restrict__ enc,
                                              const float* __restrict__ rel,
                                              const float* __restrict__ Pst,
                                              uint16_t* __restrict__ encRb) {
  const int blk = blockIdx.x;
  const int b = blk / 12;
  const int s0 = (blk % 12) * 8;
  const int t = threadIdx.x;
  __shared__ float As[RSEQ][DD + 4];
  __shared__ float Pl[RSEQ][8];

  const float* Ag = rel + (size_t)b * RSEQ * DD;
  for (int e = t; e < RSEQ * DD / 4; e += 256) {
    const int r = (e * 4) / DD, d = (e * 4) % DD;
    *(float4*)&As[r][d] = *(const float4*)&Ag[e * 4];
  }
  if (t < RSEQ * 8) {
    const int r = t >> 3, sl = t & 7;
    Pl[r][sl] = Pst[(size_t)b * RSEQ * SS + r * SS + s0 + sl];
  }
  __syncthreads();

  const float* Eb = enc + ((size_t)b * SS + s0) * DD;
  uint16_t* Ob = encRb + ((size_t)b * SS + s0) * DD;
  for (int e = t; e < 8 * DD / 4; e += 256) {
    const int sl = (e * 4) / DD, d = (e * 4) % DD;
    float4 v = ((const float4*)Eb)[e];
#pragma unroll
    for (int r = 0; r < RSEQ; ++r) {
      const float p = Pl[r][sl];
      v.x += p * As[r][d + 0];
      v.y += p * As[r][d + 1];
      v.z += p * As[r][d + 2];
      v.w += p * As[r][d + 3];
    }
    uint2 w;
    w.x = pkrhu(v.x, v.y);
    w.y = pkrhu(v.z, v.w);
    *(uint2*)&Ob[e * 4] = w;
  }
}

// ---------------------------------------------------------------------------
// Kernel 2: projection GEMM v2 — glld16-staged bf16 MFMA. Tiles 64x64,
// BK=64, 4 waves 2x2 (wave 32x32). LDS rows stride 72 elems. grid (12,72).
// ---------------------------------------------------------------------------
__global__ __launch_bounds__(256, 4) void k_proj(const uint16_t* __restrict__ Ab,
                                                 const uint16_t* __restrict__ Bt,
                                                 const float* __restrict__ pb,
                                                 float* __restrict__ Hh,
                                                 uint16_t* __restrict__ Htb) {
  const int m0 = blockIdx.x * 64;
  const int gn0 = blockIdx.y * 64;
  const bool isH = gn0 < D3;               // uniform per block
  const int n0 = isH ? gn0 : gn0 - D3;
  const int halfk = isH ? 0 : DD;
  const int t = threadIdx.x, w = t >> 6, lane = t & 63;
  const int wm = w >> 1, wn = w & 1;
  const int lm = lane & 15, q = lane >> 4;

  __shared__ __align__(16) uint16_t As[64 * 72];  // 9216 B
  __shared__ __align__(16) uint16_t Bs[64 * 72];  // 9216 B

  const char* rp[5];
  char* lp[5];
#pragma unroll
  for (int r = 0; r < 5; ++r) {
    const int idx = w + 4 * r;
    rp[r] = nullptr;
    lp[r] = nullptr;
    if (idx < 18) {
      const int ii = (idx < 9) ? idx : idx - 9;
      const int beta = ii * 1024 + lane * 16;
      const int elem = beta >> 1;
      const int row = elem / 72;
      int o = elem - row * 72;
      if (o >= 64) o = 0;  // pad lanes: safe addr, land in LDS row pad
      if (idx < 9) {
        rp[r] = (const char*)(Ab + (size_t)(m0 + row) * DD + o);
        lp[r] = (char*)As + ii * 1024;
      } else {
        rp[r] = (const char*)(Bt + (size_t)(n0 + row) * (2 * DD) + halfk + o);
        lp[r] = (char*)Bs + ii * 1024;
      }
    }
  }

  f32x4 acc[2][2];
#pragma unroll
  for (int a = 0; a < 2; ++a)
#pragma unroll
    for (int c = 0; c < 2; ++c) acc[a][c] = (f32x4){0.f, 0.f, 0.f, 0.f};

  for (int k0 = 0; k0 < DD; k0 += 64) {
    __syncthreads();
#pragma unroll
    for (int r = 0; r < 5; ++r)
      if (rp[r]) glld16(rp[r] + 2 * k0, lp[r]);
    __syncthreads();
#pragma unroll
    for (int kk = 0; kk < 2; ++kk) {
      const int ko = kk * 32 + q * 8;
      bf16x8 af[2], bf[2];
#pragma unroll
      for (int mt = 0; mt < 2; ++mt)
        af[mt] = *(const bf16x8*)&As[(wm * 32 + mt * 16 + lm) * 72 + ko];
#pragma unroll
      for (int nt = 0; nt < 2; ++nt)
        bf[nt] = *(const bf16x8*)&Bs[(wn * 32 + nt * 16 + lm) * 72 + ko];
#pragma unroll
      for (int nt = 0; nt < 2; ++nt)
#pragma unroll
        for (int mt = 0; mt < 2; ++mt)
          acc[mt][nt] = __builtin_amdgcn_mfma_f32_16x16x32_bf16(af[mt], bf[nt], acc[mt][nt], 0, 0, 0);
    }
  }

#pragma unroll
  for (int nt = 0; nt < 2; ++nt) {
    const int ncol = n0 + wn * 32 + nt * 16 + lm;
    const int mrow = m0 + wm * 32 + q * 4;
    if (isH) {
      const float bias = pb[ncol];
#pragma unroll
      for (int mt = 0; mt < 2; ++mt)
#pragma unroll
        for (int r = 0; r < 4; ++r)
          Hh[(size_t)(mrow + mt * 16 + r) * D3 + ncol] = acc[mt][nt][r] + bias;
    } else {
#pragma unroll
      for (int mt = 0; mt < 2; ++mt)
#pragma unroll
        for (int r = 0; r < 4; ++r)
          Htb[(size_t)(mrow + mt * 16 + r) * D3 + ncol] = bf16c(acc[mt][nt][r]);
    }
  }
}

// ---------------------------------------------------------------------------
// Kernel 3: pairwise GEMM v7 — glld16 staging, 4 waves 2x2, wave = 48j x
// {48,32}c. grid 768 = (b,i).
// ---------------------------------------------------------------------------
#define HTS_B (96 * 144)                 // 13824 B staged Ht
#define WOFF (HTS_B / 2)                 // 6912 elems

__global__ __launch_bounds__(256, 3) void k_pairs(const float* __restrict__ Hh,
                                                  const uint16_t* __restrict__ Htb,
                                                  const uint16_t* __restrict__ Wb,
                                                  const float* __restrict__ relb,
                                                  float* __restrict__ out) {
  const int bi = blockIdx.x;
  const int b = bi / SS, i = bi % SS;
  const int t = threadIdx.x;
  const int w = t >> 6, lane = t & 63;
  const int lm = lane & 15, q = lane >> 4;
  const int wm = w >> 1, wn = w & 1;
  const int ntn = wn ? 2 : 3;  // n-tiles this wave

  __shared__ __align__(16) float Hrow[D3];        // 9216 B (9 issues)
  __shared__ __align__(16) uint16_t Stg[12800];   // 25600 B (25 issues incl tail)

  // one-time: stage Hrow via async copy
  {
    const char* hh = (const char*)(Hh + (size_t)bi * D3);
#pragma unroll
    for (int r = 0; r < 3; ++r) {
      const int idx = w + 4 * r;
      if (idx < 9) glld16(hh + idx * 1024 + lane * 16, (char*)Hrow + idx * 1024);
    }
  }

  // per-lane k0-invariant source pointers for the 25 chunk-staging issues
  const char* rp[7];
#pragma unroll
  for (int r = 0; r < 7; ++r) {
    const int idx = w + 4 * r;
    rp[r] = nullptr;
    if (idx < 25) {
      const int beta = idx * 1024 + lane * 16;
      int elem, row, o;
      const char* base;
      if (beta < HTS_B) {
        elem = beta >> 1;
        row = elem / 72;
        o = elem - row * 72;
        base = (const char*)(Htb + ((size_t)b * SS + row) * D3);
      } else {
        elem = (beta - HTS_B) >> 1;
        row = elem / 72;
        o = elem - row * 72;
        base = (const char*)(Wb + (size_t)row * D3);  // rows up to 81 exist
      }
      if (o >= 64) o = 0;  // pad lanes: valid addr, lands in unused LDS pad
      rp[r] = base + 2 * o;
    }
  }

  f32x4 acc[3][3];
#pragma unroll
  for (int mt = 0; mt < 3; ++mt)
#pragma unroll
    for (int nt = 0; nt < 3; ++nt) acc[mt][nt] = (f32x4){0.f, 0.f, 0.f, 0.f};

  for (int k0 = 0; k0 < D3; k0 += 64) {
    __syncthreads();  // prev chunk's Stg reads done (and orders Hrow on iter 0)
#pragma unroll
    for (int r = 0; r < 7; ++r) {
      const int idx = w + 4 * r;
      if (idx < 25) glld16(rp[r] + 2 * k0, (char*)Stg + idx * 1024);
    }
    __syncthreads();  // vmcnt drain: staged data visible

#pragma unroll
    for (int kk = 0; kk < 2; ++kk) {
      const int ko = kk * 32 + q * 8;
      const float4 h0 = *(const float4*)&Hrow[k0 + ko];      // broadcast
      const float4 h1 = *(const float4*)&Hrow[k0 + ko + 4];  // broadcast
      bf16x8 af[3];
#pragma unroll
      for (int mt = 0; mt < 3; ++mt) {
        const int j = wm * 48 + mt * 16 + lm;
        union { bf16x8 v; uint32_t u[4]; } hu, pk;
        hu.v = *(const bf16x8*)&Stg[j * 72 + ko];
        pk.u[0] = pkrhu(fmaxf(lo16f(hu.u[0]) + h0.x, 0.f), fmaxf(hi16f(hu.u[0]) + h0.y, 0.f));
        pk.u[1] = pkrhu(fmaxf(lo16f(hu.u[1]) + h0.z, 0.f), fmaxf(hi16f(hu.u[1]) + h0.w, 0.f));
        pk.u[2] = pkrhu(fmaxf(lo16f(hu.u[2]) + h1.x, 0.f), fmaxf(hi16f(hu.u[2]) + h1.y, 0.f));
        pk.u[3] = pkrhu(fmaxf(lo16f(hu.u[3]) + h1.z, 0.f), fmaxf(hi16f(hu.u[3]) + h1.w, 0.f));
        af[mt] = pk.v;
      }
#pragma unroll
      for (int nt = 0; nt < 3; ++nt) {
        if (nt < ntn) {
          const int n = (wn * 3 + nt) * 16 + lm;
          const bf16x8 bf = *(const bf16x8*)&Stg[WOFF + n * 72 + ko];
#pragma unroll
          for (int mt = 0; mt < 3; ++mt)
            acc[mt][nt] = __builtin_amdgcn_mfma_f32_16x16x32_bf16(af[mt], bf, acc[mt][nt], 0, 0, 0);
        }
      }
    }
  }

  // epilogue: C layout col=lm (c), row=q*4+r (j within 16-tile)
#pragma unroll
  for (int nt = 0; nt < 3; ++nt) {
    if (nt < ntn) {
      const int c = (wn * 3 + nt) * 16 + lm;
      if (c < NC) {
        const float rb = relb[c];
        const int rr = c / 3, tg = c % 3;
#pragma unroll
        for (int mt = 0; mt < 3; ++mt) {
          const int j0 = wm * 48 + mt * 16 + q * 4;
          float* base = out + ((((size_t)b * TAG + tg) * RR + rr) * SS + i) * SS + j0;
          float4 o;
          o.x = acc[mt][nt][0] + rb;
          o.y = acc[mt][nt][1] + rb;
          o.z = acc[mt][nt][2] + rb;
          o.w = acc[mt][nt][3] + rb;
          *(float4*)base = o;
        }
      }
    }
  }
}

// ---------------------------------------------------------------------------
extern "C" void kernel_launch(void* const* d_in, const int* in_sizes, int n_in,
                              void* d_out, int out_size, void* d_ws, size_t ws_size,
                              hipStream_t stream) {
  const float* enc   = (const float*)d_in[0];  // [8,96,768]
  const float* rel   = (const float*)d_in[1];  // [24,8,768]
  const float* projW = (const float*)d_in[2];  // [1536,2304]
  const float* projb = (const float*)d_in[3];  // [2304]
  const float* relW  = (const float*)d_in[4];  // [2304,72]
  const float* relb  = (const float*)d_in[5];  // [72]
  float* out = (float*)d_out;                  // [8,3,24,96,96]

  float* Hh = (float*)d_ws;                               // 768*2304 f32
  uint16_t* Htb = (uint16_t*)(Hh + (size_t)DD * D3);      // 768*2304 bf16
  uint16_t* Wb = Htb + (size_t)DD * D3;                   // 96*2304 bf16 (80 used)
  uint16_t* Tp = Wb + (size_t)96 * D3;                    // 2304*1536 bf16
  uint16_t* Ab = Tp + (size_t)D3 * 2 * DD;                // 768*768 bf16
  float* Pst = (float*)(Ab + (size_t)DD * DD);            // 8*8*96 f32
  float* SG = Pst + (size_t)BB * RSEQ * SS;               // 8*8*104 f32

  hipMemsetAsync(SG, 0, (size_t)BB * RSEQ * 104 * sizeof(float), stream);
  k_prep0<<<1028, 256, 0, stream>>>(relW, Wb, projW, Tp, enc, rel, SG);
  k_refS<<<BB, 256, 0, stream>>>(SG, Pst);
  k_refB<<<96, 256, 0, stream>>>(enc, rel, Pst, Ab);
  k_proj<<<dim3(12, 72), 256, 0, stream>>>(Ab, Tp, projb, Hh, Htb);
  k_pairs<<<BB * SS, 256, 0, stream>>>(Hh, Htb, Wb, relb, out);
}